// Round 1
// baseline (1321.503 us; speedup 1.0000x reference)
//
#include <hip/hip_runtime.h>
#include <hip/hip_bf16.h>

typedef _Float16 f16x8 __attribute__((ext_vector_type(8)));
typedef float    f32x4 __attribute__((ext_vector_type(4)));

__device__ inline f16x8 zero8() {
    f16x8 v;
#pragma unroll
    for (int j = 0; j < 8; ++j) v[j] = (_Float16)0.f;
    return v;
}

// Pack W_ih (768x256) + W_hh (768x256) fp32 into fp16 WP[1024][512]:
//   n' = g*256 + d, g in {r, z, i_n, h_n}
//   g=0 (r):  k<256 -> Wih[d][k],      k>=256 -> Whh[d][k-256]
//   g=1 (z):  k<256 -> Wih[256+d][k],  k>=256 -> Whh[256+d][k-256]
//   g=2 (in): k<256 -> Wih[512+d][k],  k>=256 -> 0 (skipped in K-loop)
//   g=3 (hn): k<256 -> 0 (skipped),    k>=256 -> Whh[512+d][k-256]
__global__ __launch_bounds__(256) void prepack_weights(
    const float* __restrict__ Wih, const float* __restrict__ Whh,
    _Float16* __restrict__ WP)
{
    int idx = blockIdx.x * 256 + threadIdx.x;   // 1024*512 total
    if (idx >= 1024 * 512) return;
    int np = idx >> 9, k = idx & 511;
    int g = np >> 8, d = np & 255;
    float v = 0.f;
    if (g == 0)      v = (k < 256) ? Wih[d * 256 + k]         : Whh[d * 256 + (k - 256)];
    else if (g == 1) v = (k < 256) ? Wih[(256 + d) * 256 + k] : Whh[(256 + d) * 256 + (k - 256)];
    else if (g == 2) v = (k < 256) ? Wih[(512 + d) * 256 + k] : 0.f;
    else             v = (k >= 256) ? Whh[(512 + d) * 256 + (k - 256)] : 0.f;
    WP[idx] = (_Float16)v;
}

// One GRU cell over M rows:  h' = (1-z)*n + z*h,
//   r = sig(x.Wr_ih + b + h.Wr_hh + b), z likewise, n = tanh(i_n + r*h_n)
// GEMM: M x (4 groups x 64 dims) with K=512 ([x(256) | h(256)]).
// Block: 64 rows x 64 dims; 4 waves, wave w owns dims d0+16w..+15 for all 4 groups.
// hmode: 0 = h==0 (level 0 cell1), 1 = h = 0.5*(Hsrc[2m]+Hsrc[2m+1]), 2 = h = Hsrc[m]
__global__ __launch_bounds__(256) void gru_cell(
    const void* __restrict__ Xsrc, int x_is_f32, int xoff,
    const _Float16* __restrict__ Hsrc, int hmode,
    const _Float16* __restrict__ WP,
    const float* __restrict__ b_ih, const float* __restrict__ b_hh,
    _Float16* __restrict__ Hout, _Float16* __restrict__ Eout,
    int M)
{
    // LDS: 8k-interleaved so fragment ds_read_b128 is linear across the wave.
    __shared__ _Float16 Blds[4 * 64 * 64];  // g*4096 + sub*512 + n*8 + j   (32 KB)
    __shared__ _Float16 Alds[64 * 64];      // sub*512 + m*8 + j            (8 KB)

    const int tid  = threadIdx.x;
    const int m0   = (blockIdx.x >> 2) * 64;
    const int d0   = (blockIdx.x & 3) * 64;
    const int wave = tid >> 6;
    const int lane = tid & 63;
    const int quad = lane >> 4;
    const int lo   = lane & 15;

    f32x4 acc[4][4];  // [row-tile mt][group g]
#pragma unroll
    for (int a = 0; a < 4; ++a)
#pragma unroll
        for (int b = 0; b < 4; ++b) acc[a][b] = (f32x4){0.f, 0.f, 0.f, 0.f};

    const int nchunks = (hmode == 0) ? 4 : 8;  // h==0: only the x-half of K

    for (int c = 0; c < nchunks; ++c) {
        __syncthreads();
        // ---- stage B (weights): 256 rows x 64 k -> 2048 x 16B copies ----
#pragma unroll
        for (int it = 0; it < 8; ++it) {
            int flat = it * 256 + tid;       // 0..2047
            int row  = flat >> 3;            // 0..255 = g*64 + nl
            int sub  = flat & 7;
            int g = row >> 6, nl = row & 63;
            const _Float16* src = WP + (size_t)(g * 256 + d0 + nl) * 512 + c * 64 + sub * 8;
            f16x8 v = *(const f16x8*)src;
            *(f16x8*)(Blds + g * 4096 + sub * 512 + nl * 8) = v;
        }
        // ---- stage A (x or h rows): 64 rows x 64 k -> 512 x 16B ----
#pragma unroll
        for (int it = 0; it < 2; ++it) {
            int flat = it * 256 + tid;       // 0..511
            int m = flat >> 3, sub = flat & 7;
            int gm = m0 + m;
            f16x8 v;
            if (gm >= M) {
                v = zero8();
            } else if (c < 4) {              // x part of K
                int xrow = 2 * gm + xoff;
                int off  = c * 64 + sub * 8;
                if (x_is_f32) {
                    const float* s = (const float*)Xsrc + (size_t)xrow * 256 + off;
#pragma unroll
                    for (int j = 0; j < 8; ++j) v[j] = (_Float16)s[j];
                } else {
                    v = *(const f16x8*)((const _Float16*)Xsrc + (size_t)xrow * 256 + off);
                }
            } else {                         // h part of K
                int kh = (c - 4) * 64 + sub * 8;
                if (hmode == 1) {
                    f16x8 a = *(const f16x8*)(Hsrc + (size_t)(2 * gm) * 256 + kh);
                    f16x8 b = *(const f16x8*)(Hsrc + (size_t)(2 * gm + 1) * 256 + kh);
#pragma unroll
                    for (int j = 0; j < 8; ++j)
                        v[j] = (_Float16)(0.5f * ((float)a[j] + (float)b[j]));
                } else {
                    v = *(const f16x8*)(Hsrc + (size_t)gm * 256 + kh);
                }
            }
            *(f16x8*)(Alds + sub * 512 + m * 8) = v;
        }
        __syncthreads();

        const bool g2on = (c < 4);   // i_n group: x-half of K only
        const bool g3on = (c >= 4);  // h_n group: h-half of K only
#pragma unroll
        for (int ks = 0; ks < 2; ++ks) {
            int subb = ks * 4 + quad;
            f16x8 af[4];
#pragma unroll
            for (int mt = 0; mt < 4; ++mt)
                af[mt] = *(const f16x8*)(Alds + subb * 512 + (mt * 16 + lo) * 8);
            f16x8 bf0 = *(const f16x8*)(Blds + 0 * 4096 + subb * 512 + (wave * 16 + lo) * 8);
            f16x8 bf1 = *(const f16x8*)(Blds + 1 * 4096 + subb * 512 + (wave * 16 + lo) * 8);
#pragma unroll
            for (int mt = 0; mt < 4; ++mt)
                acc[mt][0] = __builtin_amdgcn_mfma_f32_16x16x32_f16(af[mt], bf0, acc[mt][0], 0, 0, 0);
#pragma unroll
            for (int mt = 0; mt < 4; ++mt)
                acc[mt][1] = __builtin_amdgcn_mfma_f32_16x16x32_f16(af[mt], bf1, acc[mt][1], 0, 0, 0);
            if (g2on) {
                f16x8 bf2 = *(const f16x8*)(Blds + 2 * 4096 + subb * 512 + (wave * 16 + lo) * 8);
#pragma unroll
                for (int mt = 0; mt < 4; ++mt)
                    acc[mt][2] = __builtin_amdgcn_mfma_f32_16x16x32_f16(af[mt], bf2, acc[mt][2], 0, 0, 0);
            }
            if (g3on) {
                f16x8 bf3 = *(const f16x8*)(Blds + 3 * 4096 + subb * 512 + (wave * 16 + lo) * 8);
#pragma unroll
                for (int mt = 0; mt < 4; ++mt)
                    acc[mt][3] = __builtin_amdgcn_mfma_f32_16x16x32_f16(af[mt], bf3, acc[mt][3], 0, 0, 0);
            }
        }
    }

    // ---- epilogue: GRU nonlinearity, wave-private ----
    const int d = d0 + wave * 16 + lo;
    const float bir = b_ih[d],       bhr = b_hh[d];
    const float biz = b_ih[256 + d], bhz = b_hh[256 + d];
    const float bin = b_ih[512 + d], bhn = b_hh[512 + d];
#pragma unroll
    for (int mt = 0; mt < 4; ++mt) {
#pragma unroll
        for (int r = 0; r < 4; ++r) {
            int m = m0 + mt * 16 + quad * 4 + r;
            if (m >= M) continue;
            float rpre = acc[mt][0][r] + bir + bhr;
            float zpre = acc[mt][1][r] + biz + bhz;
            float inp  = acc[mt][2][r] + bin;
            float hnp  = acc[mt][3][r] + bhn;
            float rg = 1.f / (1.f + __expf(-rpre));
            float zg = 1.f / (1.f + __expf(-zpre));
            float ex = __expf(2.f * (inp + rg * hnp));
            float nv = 1.f - 2.f / (ex + 1.f);        // tanh, inf-safe
            float hin = 0.f;
            if (hmode == 1)
                hin = 0.5f * ((float)Hsrc[(size_t)(2 * m) * 256 + d] +
                              (float)Hsrc[(size_t)(2 * m + 1) * 256 + d]);
            else if (hmode == 2)
                hin = (float)Hsrc[(size_t)m * 256 + d];
            float hq = (1.f - zg) * nv + zg * hin;
            Hout[(size_t)m * 256 + d] = (_Float16)hq;
            if (Eout) Eout[(size_t)m * 256 + d] = (_Float16)(0.5f * (hin + hq));
        }
    }
}

__global__ __launch_bounds__(256) void to_f32(const _Float16* __restrict__ src,
                                              float* __restrict__ dst, int n)
{
    int i = blockIdx.x * 256 + threadIdx.x;
    if (i < n) dst[i] = (float)src[i];
}

extern "C" void kernel_launch(void* const* d_in, const int* in_sizes, int n_in,
                              void* d_out, int out_size, void* d_ws, size_t ws_size,
                              hipStream_t stream) {
    const float* leaf = (const float*)d_in[0];  // 32 x 4096 x 256
    const float* Wih  = (const float*)d_in[1];  // 768 x 256
    const float* Whh  = (const float*)d_in[2];  // 768 x 256
    const float* bih  = (const float*)d_in[3];  // 768
    const float* bhh  = (const float*)d_in[4];  // 768

    char* ws = (char*)d_ws;
    _Float16* WP = (_Float16*)ws;                                  //  1 MB
    _Float16* EA = (_Float16*)(ws + (1ull << 20));                 // 32 MB
    _Float16* EB = (_Float16*)(ws + (1ull << 20) + (32ull << 20)); // 32 MB
    _Float16* HS = (_Float16*)(ws + (1ull << 20) + (64ull << 20)); // 32 MB
    _Float16* H1 = (_Float16*)(ws + (1ull << 20) + (96ull << 20)); // 32 MB

    prepack_weights<<<2048, 256, 0, stream>>>(Wih, Whh, WP);

    int n = 4096, level = 0;
    const void* xsrc = (const void*)leaf;
    int x_f32 = 1;
    _Float16* Ecur = EA;
    while (n > 1) {
        int M  = 32 * (n / 2);
        int nm = (M + 63) / 64;
        dim3 grid(nm * 4);
        // cell 1: h1 = gru(xL, h0);  h0 = pair-avg of HS (or 0 at level 0)
        gru_cell<<<grid, 256, 0, stream>>>(xsrc, x_f32, 0, HS, (level == 0) ? 0 : 1,
                                           WP, bih, bhh, H1, (_Float16*)nullptr, M);
        // cell 2: h2 = gru(xR, h1);  HS <- h2;  E' <- 0.5*(h1+h2)
        gru_cell<<<grid, 256, 0, stream>>>(xsrc, x_f32, 1, H1, 2,
                                           WP, bih, bhh, HS, Ecur, M);
        xsrc = (const void*)Ecur; x_f32 = 0;
        Ecur = (Ecur == EA) ? EB : EA;
        n >>= 1; ++level;
    }
    to_f32<<<(8192 + 255) / 256, 256, 0, stream>>>((const _Float16*)xsrc, (float*)d_out, 8192);
}

// Round 2
// 830.213 us; speedup vs baseline: 1.5918x; 1.5918x over previous
//
#include <hip/hip_runtime.h>
#include <hip/hip_bf16.h>
#include <stdint.h>

typedef _Float16 f16x8 __attribute__((ext_vector_type(8)));
typedef float    f32x4 __attribute__((ext_vector_type(4)));

// async 16-B global->LDS DMA: per-lane global src, dest = wave-uniform base + lane*16
#define GLDS16(gptr, lptr) \
  __builtin_amdgcn_global_load_lds((const __attribute__((address_space(1))) void*)(gptr), \
                                   (__attribute__((address_space(3))) void*)(lptr), 16, 0, 0)

// WPp staged layout: [c(8)][d0b(4)][g(4)][sub(8)][nl(64)][j(8)] halves.
// element = W(group g, dim d = d0b*64+nl, k = c*64+sub*8+j)
//   g=0 (r):  k<256 -> Wih[d][k],      else Whh[d][k-256]
//   g=1 (z):  k<256 -> Wih[256+d][k],  else Whh[256+d][k-256]
//   g=2 (in): k<256 -> Wih[512+d][k],  else 0   (never staged for k>=256)
//   g=3 (hn): k>=256 -> Whh[512+d][k-256], else 0 (never staged for k<256)
__global__ __launch_bounds__(256) void prepack_weights(
    const float* __restrict__ Wih, const float* __restrict__ Whh,
    _Float16* __restrict__ WP)
{
    int idx = blockIdx.x * 256 + threadIdx.x;   // 524288 total
    if (idx >= 8 * 4 * 4 * 8 * 64 * 8) return;
    int j   = idx & 7;
    int nl  = (idx >> 3) & 63;
    int sub = (idx >> 9) & 7;
    int g   = (idx >> 12) & 3;
    int d0b = (idx >> 14) & 3;
    int c   = idx >> 16;
    int k = c * 64 + sub * 8 + j;
    int d = d0b * 64 + nl;
    float v = 0.f;
    if (g == 0)      v = (k < 256) ? Wih[d * 256 + k]         : Whh[d * 256 + (k - 256)];
    else if (g == 1) v = (k < 256) ? Wih[(256 + d) * 256 + k] : Whh[(256 + d) * 256 + (k - 256)];
    else if (g == 2) v = (k < 256) ? Wih[(512 + d) * 256 + k] : 0.f;
    else             v = (k >= 256) ? Whh[(512 + d) * 256 + (k - 256)] : 0.f;
    WP[idx] = (_Float16)v;
}

// fp32 leaf -> fp16, split even/odd rows (xL / xR contiguous)
__global__ __launch_bounds__(256) void convert_split(
    const float* __restrict__ leaf, _Float16* __restrict__ XE, _Float16* __restrict__ XO)
{
    int t = blockIdx.x * 256 + threadIdx.x;     // 8388608 threads, 4 elems each
    size_t e = (size_t)t * 4;
    int row = (int)(e >> 8), col = (int)(e & 255);
    float4 v = *(const float4*)(leaf + e);
    _Float16* dst = ((row & 1) ? XO : XE) + ((size_t)(row >> 1) * 256 + col);
    union { _Float16 h[4]; uint64_t u; } p;
    p.h[0] = (_Float16)v.x; p.h[1] = (_Float16)v.y;
    p.h[2] = (_Float16)v.z; p.h[3] = (_Float16)v.w;
    *(uint64_t*)dst = p.u;
}

// GRU cell, all staging via global_load_lds DMA.
// Block: MT*16 rows x 64 dims (x4 groups). 4 waves; wave w owns dims d0b*64+w*16..+15.
// cell1 (Hout != null):  h' -> Hout[m]          (hin = Hsrc[m] or 0)
// cell2 (Hout == null):  E=0.5(h1+h') -> split Ee/Eo; HP[m/2]=pair-avg(h') -> HP
template<int MT>
__global__ __launch_bounds__(256, (MT == 8) ? 2 : 4) void gru_cell(
    const _Float16* __restrict__ Xsrc,
    const _Float16* __restrict__ Hsrc,
    const _Float16* __restrict__ WP,
    const float* __restrict__ b_ih, const float* __restrict__ b_hh,
    _Float16* __restrict__ Hout,
    _Float16* __restrict__ Ee, _Float16* __restrict__ Eo, _Float16* __restrict__ HP,
    int M)
{
    constexpr int AROW = MT * 16 * 8 + 8;   // halves per A sub-row (+16B pad -> bank shift 4)
    constexpr int BROW = 520;               // 64*8 + 8 pad
    __shared__ __align__(16) _Float16 Alds[8 * AROW];
    __shared__ __align__(16) _Float16 Blds[3 * 8 * BROW];

    const int tid  = threadIdx.x;
    const int bm   = blockIdx.x >> 2;
    const int d0b  = blockIdx.x & 3;
    const int m0   = bm * (MT * 16);
    const int wave = tid >> 6, lane = tid & 63;
    const int quad = lane >> 4, lo = lane & 15;

    const bool has_h = (Hsrc != nullptr);
    const int nch = has_h ? 8 : 4;

    f32x4 acc[MT][4];
#pragma unroll
    for (int a = 0; a < MT; ++a)
#pragma unroll
        for (int b = 0; b < 4; ++b) acc[a][b] = (f32x4){0.f, 0.f, 0.f, 0.f};

    for (int c = 0; c < nch; ++c) {
        __syncthreads();
        // ---- B: 24 DMA issues (3 active groups x 8 subs), 6 per wave ----
        {
            const size_t cb = (size_t)(c * 4 + d0b) * 4;
#pragma unroll
            for (int i = 0; i < 6; ++i) {
                int bi = wave * 6 + i;
                int slot = bi >> 3, sub = bi & 7;
                int g = (slot == 2) ? ((c < 4) ? 2 : 3) : slot;
                const _Float16* src = WP + ((cb + g) * 8 + sub) * 512 + lane * 8;
                _Float16* dst = Blds + (slot * 8 + sub) * BROW;
                GLDS16(src, dst);
            }
        }
        // ---- A: 2*MT DMA issues, MT/2 per wave ----
        {
            const _Float16* base = (c < 4) ? Xsrc : Hsrc;
            const int coloff = (c & 3) * 64;
            constexpr int IPS = MT / 4;      // issues per sub-row (8:2, 4:1)
#pragma unroll
            for (int i = 0; i < MT / 2; ++i) {
                int ai = wave * (MT / 2) + i;
                int sub = ai / IPS;
                int mh  = ai % IPS;
                int row = m0 + mh * 64 + lane;
                if (row >= M) row = M - 1;   // tail clamp (results masked in epilogue)
                const _Float16* src = base + (size_t)row * 256 + coloff + sub * 8;
                _Float16* dst = Alds + sub * AROW + mh * 64 * 8;
                GLDS16(src, dst);
            }
        }
        __syncthreads();   // drains vmcnt -> DMA visible

#pragma unroll
        for (int ks = 0; ks < 2; ++ks) {
            const int subb = ks * 4 + quad;
            f16x8 af[MT];
#pragma unroll
            for (int mt = 0; mt < MT; ++mt)
                af[mt] = *(const f16x8*)(Alds + subb * AROW + (mt * 16 + lo) * 8);
            f16x8 b0 = *(const f16x8*)(Blds + (0 * 8 + subb) * BROW + (wave * 16 + lo) * 8);
            f16x8 b1 = *(const f16x8*)(Blds + (1 * 8 + subb) * BROW + (wave * 16 + lo) * 8);
            f16x8 b2 = *(const f16x8*)(Blds + (2 * 8 + subb) * BROW + (wave * 16 + lo) * 8);
#pragma unroll
            for (int mt = 0; mt < MT; ++mt)
                acc[mt][0] = __builtin_amdgcn_mfma_f32_16x16x32_f16(af[mt], b0, acc[mt][0], 0, 0, 0);
#pragma unroll
            for (int mt = 0; mt < MT; ++mt)
                acc[mt][1] = __builtin_amdgcn_mfma_f32_16x16x32_f16(af[mt], b1, acc[mt][1], 0, 0, 0);
            if (c < 4) {
#pragma unroll
                for (int mt = 0; mt < MT; ++mt)
                    acc[mt][2] = __builtin_amdgcn_mfma_f32_16x16x32_f16(af[mt], b2, acc[mt][2], 0, 0, 0);
            } else {
#pragma unroll
                for (int mt = 0; mt < MT; ++mt)
                    acc[mt][3] = __builtin_amdgcn_mfma_f32_16x16x32_f16(af[mt], b2, acc[mt][3], 0, 0, 0);
            }
        }
    }

    // ---- epilogue ----
    const int d = d0b * 64 + wave * 16 + lo;
    const float bir = b_ih[d],       bhr = b_hh[d];
    const float biz = b_ih[256 + d], bhz = b_hh[256 + d];
    const float bin = b_ih[512 + d], bhn = b_hh[512 + d];
#pragma unroll
    for (int mt = 0; mt < MT; ++mt) {
        const int mbase = m0 + mt * 16 + quad * 4;
        float hq[4], h1v[4];
#pragma unroll
        for (int r = 0; r < 4; ++r) {
            int m = mbase + r;
            int mm = (m < M) ? m : (M - 1);
            float hin = has_h ? (float)Hsrc[(size_t)mm * 256 + d] : 0.f;
            h1v[r] = hin;
            float rg = 1.f / (1.f + __expf(-(acc[mt][0][r] + bir + bhr)));
            float zg = 1.f / (1.f + __expf(-(acc[mt][1][r] + biz + bhz)));
            float ex = __expf(2.f * (acc[mt][2][r] + bin + rg * (acc[mt][3][r] + bhn)));
            float nv = 1.f - 2.f / (ex + 1.f);
            hq[r] = (1.f - zg) * nv + zg * hin;
        }
        if (Hout) {
#pragma unroll
            for (int r = 0; r < 4; ++r)
                if (mbase + r < M) Hout[(size_t)(mbase + r) * 256 + d] = (_Float16)hq[r];
        } else {
#pragma unroll
            for (int r = 0; r < 4; ++r) {
                int m = mbase + r;
                if (m < M) {
                    float e = 0.5f * (h1v[r] + hq[r]);
                    (((m & 1) ? Eo : Ee))[(size_t)(m >> 1) * 256 + d] = (_Float16)e;
                }
            }
            if (mbase + 1 < M)
                HP[(size_t)(mbase >> 1) * 256 + d] = (_Float16)(0.5f * (hq[0] + hq[1]));
            if (mbase + 3 < M)
                HP[(size_t)((mbase >> 1) + 1) * 256 + d] = (_Float16)(0.5f * (hq[2] + hq[3]));
        }
    }
}

__global__ __launch_bounds__(256) void final_out(
    const _Float16* __restrict__ XE, const _Float16* __restrict__ XO,
    float* __restrict__ out)
{
    int i = blockIdx.x * 256 + threadIdx.x;   // 8192
    int j = i >> 8, col = i & 255;
    const _Float16* src = (j & 1) ? XO : XE;
    out[i] = (float)src[(size_t)(j >> 1) * 256 + col];
}

extern "C" void kernel_launch(void* const* d_in, const int* in_sizes, int n_in,
                              void* d_out, int out_size, void* d_ws, size_t ws_size,
                              hipStream_t stream) {
    const float* leaf = (const float*)d_in[0];
    const float* Wih  = (const float*)d_in[1];
    const float* Whh  = (const float*)d_in[2];
    const float* bih  = (const float*)d_in[3];
    const float* bhh  = (const float*)d_in[4];

    char* ws = (char*)d_ws;
    _Float16* WPp = (_Float16*)ws;                         //  1 MB
    _Float16* XAe = (_Float16*)(ws + (1ull  << 20));       // 32 MB
    _Float16* XAo = (_Float16*)(ws + (33ull << 20));       // 32 MB
    _Float16* XBe = (_Float16*)(ws + (65ull << 20));       // 16 MB
    _Float16* XBo = (_Float16*)(ws + (81ull << 20));       // 16 MB
    _Float16* H1  = (_Float16*)(ws + (97ull << 20));       // 32 MB
    _Float16* HPb = (_Float16*)(ws + (129ull << 20));      // 16 MB  (total 145 MB)

    prepack_weights<<<2048, 256, 0, stream>>>(Wih, Whh, WPp);
    convert_split<<<32768, 256, 0, stream>>>(leaf, XAe, XAo);

    _Float16 *XeC = XAe, *XoC = XAo, *XeN = XBe, *XoN = XBo;
    const _Float16* hp = nullptr;
    int M = 65536;
    for (int lev = 0; lev < 12; ++lev) {
        if (M >= 8192) {
            int bm = M / 128;
            gru_cell<8><<<bm * 4, 256, 0, stream>>>(XeC, hp, WPp, bih, bhh,
                                                    H1, nullptr, nullptr, nullptr, M);
            gru_cell<8><<<bm * 4, 256, 0, stream>>>(XoC, H1, WPp, bih, bhh,
                                                    nullptr, XeN, XoN, HPb, M);
        } else {
            int bm = (M + 63) / 64;
            gru_cell<4><<<bm * 4, 256, 0, stream>>>(XeC, hp, WPp, bih, bhh,
                                                    H1, nullptr, nullptr, nullptr, M);
            gru_cell<4><<<bm * 4, 256, 0, stream>>>(XoC, H1, WPp, bih, bhh,
                                                    nullptr, XeN, XoN, HPb, M);
        }
        hp = HPb;
        _Float16* t;
        t = XeC; XeC = XeN; XeN = t;
        t = XoC; XoC = XoN; XoN = t;
        M >>= 1;
    }
    final_out<<<32, 256, 0, stream>>>(XeC, XoC, (float*)d_out);
}

// Round 3
// 730.502 us; speedup vs baseline: 1.8090x; 1.1365x over previous
//
#include <hip/hip_runtime.h>
#include <hip/hip_bf16.h>
#include <stdint.h>

typedef _Float16 f16x8 __attribute__((ext_vector_type(8)));
typedef float    f32x4 __attribute__((ext_vector_type(4)));

// async 16-B global->LDS DMA: per-lane global src, dest = wave-uniform base + lane*16
#define GLDS16(gptr, lptr) \
  __builtin_amdgcn_global_load_lds((const __attribute__((address_space(1))) void*)(gptr), \
                                   (__attribute__((address_space(3))) void*)(lptr), 16, 0, 0)

// WP layout: [c(8)][d0b(4)][g(4)][sub(8)][nl(64)][j(8)] halves.
// element = W(group g, dim d = d0b*64+nl, k = c*64+sub*8+j)
// Block 2048 packs BC[1024]: [d]=bih[d]+bhh[d], [256+d]=bih[256+d]+bhh[256+d],
//                            [512+d]=bih[512+d], [768+d]=bhh[512+d]
__global__ __launch_bounds__(256) void prepack_weights(
    const float* __restrict__ Wih, const float* __restrict__ Whh,
    const float* __restrict__ bih, const float* __restrict__ bhh,
    _Float16* __restrict__ WP, float* __restrict__ BC)
{
    if (blockIdx.x == 2048) {
        int i = threadIdx.x;
        BC[i]       = bih[i] + bhh[i];
        BC[256 + i] = bih[256 + i] + bhh[256 + i];
        BC[512 + i] = bih[512 + i];
        BC[768 + i] = bhh[512 + i];
        return;
    }
    int idx = blockIdx.x * 256 + threadIdx.x;   // 524288 total
    int j   = idx & 7;
    int nl  = (idx >> 3) & 63;
    int sub = (idx >> 9) & 7;
    int g   = (idx >> 12) & 3;
    int d0b = (idx >> 14) & 3;
    int c   = idx >> 16;
    int k = c * 64 + sub * 8 + j;
    int d = d0b * 64 + nl;
    float v = 0.f;
    if (g == 0)      v = (k < 256) ? Wih[d * 256 + k]         : Whh[d * 256 + (k - 256)];
    else if (g == 1) v = (k < 256) ? Wih[(256 + d) * 256 + k] : Whh[(256 + d) * 256 + (k - 256)];
    else if (g == 2) v = (k < 256) ? Wih[(512 + d) * 256 + k] : 0.f;
    else             v = (k >= 256) ? Whh[(512 + d) * 256 + (k - 256)] : 0.f;
    WP[idx] = (_Float16)v;
}

// fp32 leaf -> fp16, split even/odd rows (xL / xR contiguous)
__global__ __launch_bounds__(256) void convert_split(
    const float* __restrict__ leaf, _Float16* __restrict__ XE, _Float16* __restrict__ XO)
{
    int t = blockIdx.x * 256 + threadIdx.x;
    size_t e = (size_t)t * 4;
    int row = (int)(e >> 8), col = (int)(e & 255);
    float4 v = *(const float4*)(leaf + e);
    _Float16* dst = ((row & 1) ? XO : XE) + ((size_t)(row >> 1) * 256 + col);
    union { _Float16 h[4]; uint64_t u; } p;
    p.h[0] = (_Float16)v.x; p.h[1] = (_Float16)v.y;
    p.h[2] = (_Float16)v.z; p.h[3] = (_Float16)v.w;
    *(uint64_t*)dst = p.u;
}

// GRU cell. Pipelined: A double-buffered, issued one compute-phase ahead.
// cell1 (Hout != null): h' -> Hout[m]        (hin = Hsrc[m] or 0)
// cell2 (Hout == null): E=0.5(hin+h') -> Ee/Eo split; HP[m/2] = pair-avg(h')
template<int MT, bool SWIZ>
__global__ __launch_bounds__(256, (MT == 8) ? 2 : 3) void gru_cell(
    const _Float16* __restrict__ Xsrc,
    const _Float16* __restrict__ Hsrc,
    const _Float16* __restrict__ WP,
    const float* __restrict__ BC,
    _Float16* __restrict__ Hout,
    _Float16* __restrict__ Ee, _Float16* __restrict__ Eo, _Float16* __restrict__ HP,
    int M)
{
    constexpr int AROW = MT * 16 * 8 + 8;   // +16B pad -> 4-bank shift per sub-row
    constexpr int ASZ  = 8 * AROW;
    constexpr int BROW = 520;               // 64*8 + 8 pad
    __shared__ __align__(16) _Float16 Alds[2 * ASZ];          // double-buffered
    __shared__ __align__(16) _Float16 Blds[3 * 8 * BROW];

    const int tid  = threadIdx.x;
    int bm, d0b;
    if (SWIZ) {  // siblings (same bm, 4 d0b) share blockIdx%8 -> same XCD
        int xcd = blockIdx.x & 7, slot = blockIdx.x >> 3;
        d0b = slot & 3;
        bm  = (slot >> 2) * 8 + xcd;
    } else {
        bm = blockIdx.x >> 2; d0b = blockIdx.x & 3;
    }
    const int m0   = bm * (MT * 16);
    const int wave = tid >> 6, lane = tid & 63;
    const int quad = lane >> 4, lo = lane & 15;

    const bool has_h = (Hsrc != nullptr);
    const int nch = has_h ? 8 : 4;

    f32x4 acc[MT][4];
#pragma unroll
    for (int a = 0; a < MT; ++a)
#pragma unroll
        for (int b = 0; b < 4; ++b) acc[a][b] = (f32x4){0.f, 0.f, 0.f, 0.f};
    float hinv[MT][4];

    auto issueA = [&](int c) {
        const _Float16* base = (c < 4) ? Xsrc : Hsrc;
        const int coloff = (c & 3) * 64;
        _Float16* Ab = Alds + (c & 1) * ASZ;
        constexpr int IPS = MT / 4;          // issues per sub-row
#pragma unroll
        for (int i = 0; i < MT / 2; ++i) {
            int ai = wave * (MT / 2) + i;
            int sub = ai / IPS, mh = ai % IPS;
            int row = m0 + mh * 64 + lane;
            if (MT == 4 && row >= M) row = M - 1;   // tail clamp
            GLDS16(base + (size_t)row * 256 + coloff + sub * 8,
                   Ab + sub * AROW + mh * 64 * 8);
        }
    };

    issueA(0);

    for (int c = 0; c < nch; ++c) {
        __syncthreads();   // barrier1: drains A(c) (issued ~1 compute earlier); Blds reusable
        {  // B: 24 DMA issues (3 active groups x 8 subs), 6 per wave
            const size_t cb = (size_t)(c * 4 + d0b) * 4;
#pragma unroll
            for (int i = 0; i < 6; ++i) {
                int bi = wave * 6 + i;
                int slot = bi >> 3, sub = bi & 7;
                int g = (slot == 2) ? ((c < 4) ? 2 : 3) : slot;
                GLDS16(WP + ((cb + g) * 8 + sub) * 512 + lane * 8,
                       Blds + (slot * 8 + sub) * BROW);
            }
        }
        __syncthreads();   // barrier2: drains B(c) (L2-hot, short)
        if (c + 1 < nch) issueA(c + 1);   // in flight during compute(c)

        const _Float16* Ab = Alds + (c & 1) * ASZ;
#pragma unroll
        for (int ks = 0; ks < 2; ++ks) {
            const int subb = ks * 4 + quad;
            f16x8 af[MT];
#pragma unroll
            for (int mt = 0; mt < MT; ++mt)
                af[mt] = *(const f16x8*)(Ab + subb * AROW + (mt * 16 + lo) * 8);
            f16x8 b0 = *(const f16x8*)(Blds + (0 * 8 + subb) * BROW + (wave * 16 + lo) * 8);
            f16x8 b1 = *(const f16x8*)(Blds + (1 * 8 + subb) * BROW + (wave * 16 + lo) * 8);
            f16x8 b2 = *(const f16x8*)(Blds + (2 * 8 + subb) * BROW + (wave * 16 + lo) * 8);
#pragma unroll
            for (int mt = 0; mt < MT; ++mt)
                acc[mt][0] = __builtin_amdgcn_mfma_f32_16x16x32_f16(af[mt], b0, acc[mt][0], 0, 0, 0);
#pragma unroll
            for (int mt = 0; mt < MT; ++mt)
                acc[mt][1] = __builtin_amdgcn_mfma_f32_16x16x32_f16(af[mt], b1, acc[mt][1], 0, 0, 0);
            if (c < 4) {
#pragma unroll
                for (int mt = 0; mt < MT; ++mt)
                    acc[mt][2] = __builtin_amdgcn_mfma_f32_16x16x32_f16(af[mt], b2, acc[mt][2], 0, 0, 0);
            } else {
#pragma unroll
                for (int mt = 0; mt < MT; ++mt)
                    acc[mt][3] = __builtin_amdgcn_mfma_f32_16x16x32_f16(af[mt], b2, acc[mt][3], 0, 0, 0);
            }
        }

        // capture hin from LDS while this chunk holds our dim-columns of Hsrc
        if (has_h && c == 4 + d0b) {
            const int colw = wave * 16 + lo;
            const int sub = colw >> 3, j = colw & 7;
#pragma unroll
            for (int mt = 0; mt < MT; ++mt)
#pragma unroll
                for (int r = 0; r < 4; ++r)
                    hinv[mt][r] = (float)Ab[sub * AROW + (mt * 16 + quad * 4 + r) * 8 + j];
        }
    }

    // ---- epilogue (no global loads) ----
    const int d = d0b * 64 + wave * 16 + lo;
    const float brz0 = BC[d];        // bir+bhr
    const float brz1 = BC[256 + d];  // biz+bhz
    const float bni  = BC[512 + d];  // bin
    const float bnh  = BC[768 + d];  // bhn
#pragma unroll
    for (int mt = 0; mt < MT; ++mt) {
        const int mbase = m0 + mt * 16 + quad * 4;
        float hq[4], h1v[4];
#pragma unroll
        for (int r = 0; r < 4; ++r) {
            float hin = has_h ? hinv[mt][r] : 0.f;
            h1v[r] = hin;
            float rg = 1.f / (1.f + __expf(-(acc[mt][0][r] + brz0)));
            float zg = 1.f / (1.f + __expf(-(acc[mt][1][r] + brz1)));
            float ex = __expf(2.f * (acc[mt][2][r] + bni + rg * (acc[mt][3][r] + bnh)));
            float nv = 1.f - 2.f / (ex + 1.f);
            hq[r] = (1.f - zg) * nv + zg * hin;
        }
        if (Hout) {
#pragma unroll
            for (int r = 0; r < 4; ++r)
                if (MT == 8 || mbase + r < M)
                    Hout[(size_t)(mbase + r) * 256 + d] = (_Float16)hq[r];
        } else {
#pragma unroll
            for (int r = 0; r < 4; ++r) {
                int m = mbase + r;
                if (MT == 8 || m < M)
                    (((m & 1) ? Eo : Ee))[(size_t)(m >> 1) * 256 + d] =
                        (_Float16)(0.5f * (h1v[r] + hq[r]));
            }
            if (MT == 8 || mbase + 1 < M)
                HP[(size_t)(mbase >> 1) * 256 + d] = (_Float16)(0.5f * (hq[0] + hq[1]));
            if (MT == 8 || mbase + 3 < M)
                HP[(size_t)((mbase >> 1) + 1) * 256 + d] = (_Float16)(0.5f * (hq[2] + hq[3]));
        }
    }
}

__global__ __launch_bounds__(256) void final_out(
    const _Float16* __restrict__ XE, const _Float16* __restrict__ XO,
    float* __restrict__ out)
{
    int i = blockIdx.x * 256 + threadIdx.x;   // 8192
    int j = i >> 8, col = i & 255;
    const _Float16* src = (j & 1) ? XO : XE;
    out[i] = (float)src[(size_t)(j >> 1) * 256 + col];
}

extern "C" void kernel_launch(void* const* d_in, const int* in_sizes, int n_in,
                              void* d_out, int out_size, void* d_ws, size_t ws_size,
                              hipStream_t stream) {
    const float* leaf = (const float*)d_in[0];
    const float* Wih  = (const float*)d_in[1];
    const float* Whh  = (const float*)d_in[2];
    const float* bih  = (const float*)d_in[3];
    const float* bhh  = (const float*)d_in[4];

    char* ws = (char*)d_ws;
    _Float16* WPp = (_Float16*)ws;                         //  1 MB
    _Float16* XAe = (_Float16*)(ws + (1ull  << 20));       // 32 MB
    _Float16* XAo = (_Float16*)(ws + (33ull << 20));       // 32 MB
    _Float16* XBe = (_Float16*)(ws + (65ull << 20));       // 16 MB
    _Float16* XBo = (_Float16*)(ws + (81ull << 20));       // 16 MB
    _Float16* H1  = (_Float16*)(ws + (97ull << 20));       // 32 MB
    _Float16* HPb = (_Float16*)(ws + (129ull << 20));      // 16 MB
    float*    BCp = (float*)(ws + (145ull << 20));         //  4 KB

    prepack_weights<<<2049, 256, 0, stream>>>(Wih, Whh, bih, bhh, WPp, BCp);
    convert_split<<<32768, 256, 0, stream>>>(leaf, XAe, XAo);

    _Float16 *XeC = XAe, *XoC = XAo, *XeN = XBe, *XoN = XBo;
    const _Float16* hp = nullptr;
    int M = 65536;
    for (int lev = 0; lev < 12; ++lev) {
        if (M >= 8192) {
            int grid = (M / 128) * 4;
            gru_cell<8, true><<<grid, 256, 0, stream>>>(XeC, hp, WPp, BCp,
                                                        H1, nullptr, nullptr, nullptr, M);
            gru_cell<8, true><<<grid, 256, 0, stream>>>(XoC, H1, WPp, BCp,
                                                        nullptr, XeN, XoN, HPb, M);
        } else {
            int nbm = (M + 63) / 64;
            int grid = nbm * 4;
            if ((nbm & 7) == 0) {
                gru_cell<4, true><<<grid, 256, 0, stream>>>(XeC, hp, WPp, BCp,
                                                            H1, nullptr, nullptr, nullptr, M);
                gru_cell<4, true><<<grid, 256, 0, stream>>>(XoC, H1, WPp, BCp,
                                                            nullptr, XeN, XoN, HPb, M);
            } else {
                gru_cell<4, false><<<grid, 256, 0, stream>>>(XeC, hp, WPp, BCp,
                                                             H1, nullptr, nullptr, nullptr, M);
                gru_cell<4, false><<<grid, 256, 0, stream>>>(XoC, H1, WPp, BCp,
                                                             nullptr, XeN, XoN, HPb, M);
            }
        }
        hp = HPb;
        _Float16* t;
        t = XeC; XeC = XeN; XeN = t;
        t = XoC; XoC = XoN; XoN = t;
        M >>= 1;
    }
    final_out<<<32, 256, 0, stream>>>(XeC, XoC, (float*)d_out);
}